// Round 12
// baseline (63.749 us; speedup 1.0000x reference)
//
#include <hip/hip_runtime.h>
#include <math.h>

#define MROWS 32768   // B*T
#define DDIM  1024
#define EDIM  64
#define NCH   64      // K-chunks of 16
#define TILEM 32      // rows per block; grid = 1024 -> 4 blocks/CU

typedef _Float16 f16x8 __attribute__((ext_vector_type(8)));
typedef float    f32x16 __attribute__((ext_vector_type(16)));

// WS layout per chunk c (4096 halves = 8 KB), B-frag-linear (verified R4-R11):
//   half index = c*4096 + nf*512 + lane*8 + j  (+2048 for lo plane)
//   B frag (32x32x16): col = nf*32 + (lane&31), k = (lane>>5)*8 + j
__global__ __launch_bounds__(256)
void convW_kernel(const float* __restrict__ Wr, const float* __restrict__ Wn,
                  unsigned short* __restrict__ ws) {
    int gid = blockIdx.x * 256 + threadIdx.x;   // 131072 total
    int c32 = gid & 31;
    int j   = (gid >> 5) & 7;
    int lhi = (gid >> 8) & 1;
    int nf  = (gid >> 9) & 3;
    int c   = gid >> 11;
    int lane = lhi * 32 + c32;
    int k   = c * 16 + lhi * 8 + j;
    int col = nf * 32 + c32;                    // 0..63 route, 64..127 noise
    float w = (col < EDIM) ? Wr[k * EDIM + col] : Wn[k * EDIM + (col - EDIM)];
    _Float16 hi = (_Float16)w;
    _Float16 lo = (_Float16)((w - (float)hi) * 2048.0f);
    union { _Float16 h; unsigned short u; } cv;
    size_t base = (size_t)c * 4096 + nf * 512 + lane * 8 + j;
    cv.h = hi; ws[base]        = cv.u;
    cv.h = lo; ws[base + 2048] = cv.u;
}

__global__ __launch_bounds__(256, 4)
void router_mfma(const float* __restrict__ X,
                 const unsigned short* __restrict__ WS,
                 const float* __restrict__ br_g,
                 const float* __restrict__ bn_g,
                 const float* __restrict__ U,
                 float* __restrict__ out)
{
    // Ah [2buf][2p][32][24] halves (6144 B) | B ring [4][8192 B] (32768 B)
    // Epilogue union: Lf[32][132] f32 (16896 B)
    __shared__ alignas(16) unsigned char smem[38912];
    unsigned short* Ah = (unsigned short*)smem;
    unsigned short* Bh = (unsigned short*)(smem + 6144);
    float*          Lf = (float*)smem;

    const int t    = threadIdx.x;
    const int lane = t & 63;
    const int wid  = t >> 6;                  // 0..3: nf group (B-col group)
    const int rowBase = blockIdx.x * TILEM;
    const int start   = (blockIdx.x & 7) * 8; // multiple of 8: ring/abuf parity safe

    // A staging map: thread -> (row, 2 consecutive k)
    const int arow = t >> 3;        // 0..31
    const int akk  = (t & 7) * 2;   // 0,2,..,14
    const float* xbase = X + (size_t)(rowBase + arow) * DDIM + akk;

    f32x16 acc0, acc1;
#pragma unroll
    for (int i = 0; i < 16; ++i) { acc0[i] = 0.f; acc1[i] = 0.f; }

    auto stageB = [&](int c, int ring) {   // 2 x 1 KB DMA per wave = full 8 KB/chunk
        const char* src = (const char*)WS + (size_t)c * 8192 + wid * 2048 + lane * 16;
        char* dst = (char*)(smem + 6144) + ring * 8192 + wid * 2048 + lane * 16;
        __builtin_amdgcn_global_load_lds(
            (const __attribute__((address_space(1))) void*)src,
            (__attribute__((address_space(3))) void*)dst, 16, 0, 0);
        __builtin_amdgcn_global_load_lds(
            (const __attribute__((address_space(1))) void*)(src + 1024),
            (__attribute__((address_space(3))) void*)(dst + 1024), 16, 0, 0);
    };

    auto convA = [&](float2 xv, int abuf) {
        _Float16 h0 = (_Float16)xv.x;
        _Float16 h1 = (_Float16)xv.y;
        _Float16 l0 = (_Float16)((xv.x - (float)h0) * 2048.0f);
        _Float16 l1 = (_Float16)((xv.y - (float)h1) * 2048.0f);
        union { _Float16 h[2]; unsigned int u; } ph, pl;
        ph.h[0] = h0; ph.h[1] = h1; pl.h[0] = l0; pl.h[1] = l1;
        *(unsigned int*)(Ah + ((abuf * 2 + 0) * 32 + arow) * 24 + akk) = ph.u;
        *(unsigned int*)(Ah + ((abuf * 2 + 1) * 32 + arow) * 24 + akk) = pl.u;
    };

    auto compute = [&](int abuf, int ring) {   // 3 MFMA per wave per chunk
        const unsigned short* Ab = Ah + abuf * 1536;
        const int aoff = (lane & 31) * 24 + (lane >> 5) * 8;
        f16x8 ahi = *(const f16x8*)(Ab + aoff);
        f16x8 alo = *(const f16x8*)(Ab + 768 + aoff);
        const unsigned short* Bb = Bh + ring * 4096 + wid * 512 + lane * 8;
        f16x8 bhi = *(const f16x8*)(Bb);
        f16x8 blo = *(const f16x8*)(Bb + 2048);
        __builtin_amdgcn_s_setprio(1);
        acc0 = __builtin_amdgcn_mfma_f32_32x32x16_f16(ahi, bhi, acc0, 0, 0, 0);
        acc1 = __builtin_amdgcn_mfma_f32_32x32x16_f16(ahi, blo, acc1, 0, 0, 0);
        acc1 = __builtin_amdgcn_mfma_f32_32x32x16_f16(alo, bhi, acc1, 0, 0, 0);
        __builtin_amdgcn_s_setprio(0);
    };

    // ---- prologue: chunks start,start+1 staged; X(start) converted; X(start+1) live ----
    float2 x0v = *(const float2*)(xbase + (size_t)start * 16);
    stageB(start, 0);
    stageB((start + 1) & 63, 1);
    float2 xA = *(const float2*)(xbase + (size_t)((start + 1) & 63) * 16);
    float2 xB;
    convA(x0v, 0);
    asm volatile("s_waitcnt vmcnt(3) lgkmcnt(0)" ::: "memory");
    __builtin_amdgcn_sched_barrier(0);
    __builtin_amdgcn_s_barrier();

    // phase c: issue X(c+2) + DMA(c+2) | compute(c) | convA(c+1) |
    //          vmcnt(3)+lgkmcnt(0) (retire DMA(c+1), keep 3 newest in flight) | s_barrier
#define PH(C, CUR, NXT)                                                        \
    {                                                                          \
        const int cc = start + (C);                                            \
        const int cL = (cc + 2) & 63;                                          \
        NXT = *(const float2*)(xbase + (size_t)cL * 16);                       \
        stageB(cL, (cc + 2) & 3);                                              \
        compute(cc & 1, cc & 3);                                               \
        convA(CUR, (cc + 1) & 1);                                              \
        asm volatile("s_waitcnt vmcnt(3) lgkmcnt(0)" ::: "memory");            \
        __builtin_amdgcn_sched_barrier(0);                                     \
        __builtin_amdgcn_s_barrier();                                          \
    }

    for (int i = 0; i < NCH; i += 2) {
        PH(i,     xA, xB);
        PH(i + 1, xB, xA);
    }
#undef PH

    asm volatile("s_waitcnt vmcnt(0) lgkmcnt(0)" ::: "memory");
    __syncthreads();   // full drain (wrapped DMAs) before smem reuse

    // ---- epilogue: combine hi/lo, logits tile into LDS ----
    const float inv2048 = 1.0f / 2048.0f;
    const int lcol = wid * 32 + (lane & 31);   // 0..63 route, 64..127 noise
#pragma unroll
    for (int reg = 0; reg < 16; ++reg) {
        int r = (reg & 3) + 8 * (reg >> 2) + 4 * (lane >> 5);
        Lf[r * 132 + lcol] = acc0[reg] + acc1[reg] * inv2048;
    }
    __syncthreads();

    // ---- bias + softplus-noise + butterfly top-2 + writes (8 rows/wave) ----
    const float brv = br_g[lane];
    const float bnv = bn_g[lane];
#pragma unroll 2
    for (int r8 = 0; r8 < 8; ++r8) {
        int lrow = wid * 8 + r8;
        int grow = rowBase + lrow;
        float lr = Lf[lrow * 132 + lane] + brv;
        float ln = Lf[lrow * 132 + 64 + lane] + bnv;
        float u  = U[(size_t)grow * EDIM + lane];
        float noisy = lr + u * log1pf(expf(ln));

        float m1 = noisy; int i1 = lane;
        float m2 = -INFINITY; int i2 = 64;
#pragma unroll
        for (int s = 1; s < 64; s <<= 1) {
            float om1 = __shfl_xor(m1, s); int oi1 = __shfl_xor(i1, s);
            float om2 = __shfl_xor(m2, s); int oi2 = __shfl_xor(i2, s);
            bool aw = (m1 > om1) || (m1 == om1 && i1 < oi1);
            float w1  = aw ? m1 : om1;  int wi1  = aw ? i1 : oi1;
            float c2a = aw ? m2 : om2;  int c2ai = aw ? i2 : oi2;
            float c2b = aw ? om1 : m1;  int c2bi = aw ? oi1 : i1;
            bool bw = (c2b > c2a) || (c2b == c2a && c2bi < c2ai);
            m1 = w1; i1 = wi1;
            m2 = bw ? c2b : c2a;
            i2 = bw ? c2bi : c2ai;
        }
        float e2  = expf(m2 - m1);
        float inv = 1.0f / (1.0f + e2);
        float p   = (lane == i1) ? inv : ((lane == i2) ? e2 * inv : 0.0f);
        out[(size_t)grow * EDIM + lane] = p;
        if (lane < 2)
            out[(size_t)MROWS * EDIM + (size_t)grow * 2 + lane] =
                (float)(lane == 0 ? i1 : i2);
    }
}

extern "C" void kernel_launch(void* const* d_in, const int* in_sizes, int n_in,
                              void* d_out, int out_size, void* d_ws, size_t ws_size,
                              hipStream_t stream) {
    const float* X  = (const float*)d_in[0];  // mh_output [8,4096,1024]
    const float* Wr = (const float*)d_in[1];  // W_route   [1024,64]
    const float* br = (const float*)d_in[2];  // b_route   [64]
    const float* Wn = (const float*)d_in[3];  // W_noise   [1024,64]
    const float* bn = (const float*)d_in[4];  // b_noise   [64]
    const float* U  = (const float*)d_in[5];  // noise_u   [8,4096,64]
    (void)in_sizes; (void)n_in; (void)ws_size; // uses 512 KB of d_ws
    unsigned short* ws16 = (unsigned short*)d_ws;
    convW_kernel<<<512, 256, 0, stream>>>(Wr, Wn, ws16);
    router_mfma<<<MROWS / TILEM, 256, 0, stream>>>(X, ws16, br, bn, U, (float*)d_out);
}

// Round 13
// 62.584 us; speedup vs baseline: 1.0186x; 1.0186x over previous
//
#include <hip/hip_runtime.h>
#include <math.h>

#define MROWS 32768   // B*T
#define DDIM  1024
#define EDIM  64
#define NCH   64      // K-chunks of 16
#define TILEM 32      // rows per block; grid = 1024 -> 4 blocks/CU

typedef _Float16 f16x8 __attribute__((ext_vector_type(8)));
typedef float    f32x16 __attribute__((ext_vector_type(16)));

// WS layout per chunk c (4096 halves = 8 KB), B-frag-linear (verified R4-R12):
//   half index = c*4096 + nf*512 + lane*8 + j  (+2048 for lo plane)
//   B frag (32x32x16): col = nf*32 + (lane&31), k = (lane>>5)*8 + j
//   nf: 0,1 = route col-halves; 2,3 = noise col-halves
__global__ __launch_bounds__(256)
void convW_kernel(const float* __restrict__ Wr, const float* __restrict__ Wn,
                  unsigned short* __restrict__ ws) {
    int gid = blockIdx.x * 256 + threadIdx.x;   // 131072 total
    int c32 = gid & 31;
    int j   = (gid >> 5) & 7;
    int lhi = (gid >> 8) & 1;
    int nf  = (gid >> 9) & 3;
    int c   = gid >> 11;
    int lane = lhi * 32 + c32;
    int k   = c * 16 + lhi * 8 + j;
    int col = nf * 32 + c32;                    // 0..63 route, 64..127 noise
    float w = (col < EDIM) ? Wr[k * EDIM + col] : Wn[k * EDIM + (col - EDIM)];
    _Float16 hi = (_Float16)w;
    _Float16 lo = (_Float16)((w - (float)hi) * 2048.0f);   // scaled: no fp16 denorm
    union { _Float16 h; unsigned short u; } cv;
    size_t base = (size_t)c * 4096 + nf * 512 + lane * 8 + j;
    cv.h = hi; ws[base]        = cv.u;
    cv.h = lo; ws[base + 2048] = cv.u;
}

__global__ __launch_bounds__(256, 4)
void router_mfma(const float* __restrict__ X,
                 const unsigned short* __restrict__ WS,
                 const float* __restrict__ br_g,
                 const float* __restrict__ bn_g,
                 const float* __restrict__ U,
                 float* __restrict__ out)
{
    // GEMM: Ah [2buf][2p][32][24] halves (6144 B) | Bh [2buf][4096] halves (16384 B)
    // Epilogue union: Lf[32][132] f32 (16896 B)
    __shared__ alignas(16) unsigned char smem[22528];
    unsigned short* Ah = (unsigned short*)smem;
    unsigned short* Bh = (unsigned short*)(smem + 6144);
    float*          Lf = (float*)smem;

    const int t    = threadIdx.x;
    const int lane = t & 63;
    const int wid  = t >> 6;                  // 0..3: nf group (B-col group)
    const int rowBase = blockIdx.x * TILEM;
    const int start   = (blockIdx.x & 7) * 8; // chunk-order rotation (de-convoy WS)

    // A staging map: thread -> (row, 2 consecutive k)
    const int arow = t >> 3;        // 0..31
    const int akk  = (t & 7) * 2;   // 0,2,..,14
    const float* xbase = X + (size_t)(rowBase + arow) * DDIM + akk;

    f32x16 acc0, acc1;
#pragma unroll
    for (int i = 0; i < 16; ++i) { acc0[i] = 0.f; acc1[i] = 0.f; }

    auto stageB = [&](int c, int buf) {   // 2 x 1 KB DMA per wave = full 8 KB/chunk
        const char* src = (const char*)WS + (size_t)c * 8192 + wid * 2048 + lane * 16;
        char* dst = (char*)(smem + 6144) + buf * 8192 + wid * 2048 + lane * 16;
        __builtin_amdgcn_global_load_lds(
            (const __attribute__((address_space(1))) void*)src,
            (__attribute__((address_space(3))) void*)dst, 16, 0, 0);
        __builtin_amdgcn_global_load_lds(
            (const __attribute__((address_space(1))) void*)(src + 1024),
            (__attribute__((address_space(3))) void*)(dst + 1024), 16, 0, 0);
    };

    auto convA = [&](float2 xv, int buf) {  // 2 elems/thread -> hi/lo planes
        _Float16 h0 = (_Float16)xv.x;
        _Float16 h1 = (_Float16)xv.y;
        _Float16 l0 = (_Float16)((xv.x - (float)h0) * 2048.0f);
        _Float16 l1 = (_Float16)((xv.y - (float)h1) * 2048.0f);
        union { _Float16 h[2]; unsigned int u; } ph, pl;
        ph.h[0] = h0; ph.h[1] = h1; pl.h[0] = l0; pl.h[1] = l1;
        *(unsigned int*)(Ah + ((buf * 2 + 0) * 32 + arow) * 24 + akk) = ph.u;
        *(unsigned int*)(Ah + ((buf * 2 + 1) * 32 + arow) * 24 + akk) = pl.u;
    };

    auto compute = [&](int buf) {           // 3 MFMA per wave per chunk
        const unsigned short* Ab = Ah + (buf * 2) * 768;   // 32*24 = 768
        const int aoff = (lane & 31) * 24 + (lane >> 5) * 8;
        f16x8 ahi = *(const f16x8*)(Ab + aoff);
        f16x8 alo = *(const f16x8*)(Ab + 768 + aoff);
        const unsigned short* Bb = Bh + buf * 4096 + wid * 512 + lane * 8;
        f16x8 bhi = *(const f16x8*)(Bb);
        f16x8 blo = *(const f16x8*)(Bb + 2048);
        acc0 = __builtin_amdgcn_mfma_f32_32x32x16_f16(ahi, bhi, acc0, 0, 0, 0);
        acc1 = __builtin_amdgcn_mfma_f32_32x32x16_f16(ahi, blo, acc1, 0, 0, 0);
        acc1 = __builtin_amdgcn_mfma_f32_32x32x16_f16(alo, bhi, acc1, 0, 0, 0);
    };

    // ---- prologue: chunk `start` in buf0; X pipeline 2 deep ----
    float2 xA = *(const float2*)(xbase + (size_t)start * 16);
    stageB(start, 0);
    convA(xA, 0);
    xA = *(const float2*)(xbase + (size_t)((start + 1) & 63) * 16);
    float2 xB = *(const float2*)(xbase + (size_t)((start + 2) & 63) * 16);
    __syncthreads();

    // phase i: stage c(i+1)->buf^1 | issue x-load c(i+3) | compute buf |
    //          convA c(i+1) -> buf^1 | barrier.  (CUR holds c(i+1), NXT c(i+2))
#define PHASE(I, CUR, NXT)                                                     \
    {                                                                          \
        const int buf = (I) & 1;                                               \
        if ((I) + 1 < NCH) stageB((start + (I) + 1) & 63, buf ^ 1);            \
        float2 tmp = CUR;                                                      \
        if ((I) + 3 < NCH)                                                     \
            tmp = *(const float2*)(xbase + (size_t)((start + (I) + 3) & 63) * 16); \
        compute(buf);                                                          \
        if ((I) + 1 < NCH) convA(CUR, buf ^ 1);                                \
        CUR = tmp;                                                             \
        __syncthreads();                                                       \
    }

    for (int i = 0; i < NCH; i += 2) {
        PHASE(i,     xA, xB);
        PHASE(i + 1, xB, xA);
    }
#undef PHASE

    // ---- epilogue: combine hi/lo, logits tile into LDS ----
    const float inv2048 = 1.0f / 2048.0f;
    const int lcol = wid * 32 + (lane & 31);   // 0..63 route, 64..127 noise
#pragma unroll
    for (int reg = 0; reg < 16; ++reg) {
        int r = (reg & 3) + 8 * (reg >> 2) + 4 * (lane >> 5);
        Lf[r * 132 + lcol] = acc0[reg] + acc1[reg] * inv2048;
    }
    __syncthreads();

    // ---- bias + softplus-noise + butterfly top-2 + writes (8 rows/wave) ----
    const float brv = br_g[lane];
    const float bnv = bn_g[lane];
#pragma unroll 2
    for (int r8 = 0; r8 < 8; ++r8) {
        int lrow = wid * 8 + r8;
        int grow = rowBase + lrow;
        float lr = Lf[lrow * 132 + lane] + brv;
        float ln = Lf[lrow * 132 + 64 + lane] + bnv;
        float u  = U[(size_t)grow * EDIM + lane];
        float noisy = lr + u * log1pf(expf(ln));

        float m1 = noisy; int i1 = lane;
        float m2 = -INFINITY; int i2 = 64;
#pragma unroll
        for (int s = 1; s < 64; s <<= 1) {
            float om1 = __shfl_xor(m1, s); int oi1 = __shfl_xor(i1, s);
            float om2 = __shfl_xor(m2, s); int oi2 = __shfl_xor(i2, s);
            bool aw = (m1 > om1) || (m1 == om1 && i1 < oi1);
            float w1  = aw ? m1 : om1;  int wi1  = aw ? i1 : oi1;
            float c2a = aw ? m2 : om2;  int c2ai = aw ? i2 : oi2;
            float c2b = aw ? om1 : m1;  int c2bi = aw ? oi1 : i1;
            bool bw = (c2b > c2a) || (c2b == c2a && c2bi < c2ai);
            m1 = w1; i1 = wi1;
            m2 = bw ? c2b : c2a;
            i2 = bw ? c2bi : c2ai;
        }
        float e2  = expf(m2 - m1);
        float inv = 1.0f / (1.0f + e2);
        float p   = (lane == i1) ? inv : ((lane == i2) ? e2 * inv : 0.0f);
        out[(size_t)grow * EDIM + lane] = p;
        if (lane < 2)
            out[(size_t)MROWS * EDIM + (size_t)grow * 2 + lane] =
                (float)(lane == 0 ? i1 : i2);
    }
}

extern "C" void kernel_launch(void* const* d_in, const int* in_sizes, int n_in,
                              void* d_out, int out_size, void* d_ws, size_t ws_size,
                              hipStream_t stream) {
    const float* X  = (const float*)d_in[0];  // mh_output [8,4096,1024]
    const float* Wr = (const float*)d_in[1];  // W_route   [1024,64]
    const float* br = (const float*)d_in[2];  // b_route   [64]
    const float* Wn = (const float*)d_in[3];  // W_noise   [1024,64]
    const float* bn = (const float*)d_in[4];  // b_noise   [64]
    const float* U  = (const float*)d_in[5];  // noise_u   [8,4096,64]
    (void)in_sizes; (void)n_in; (void)ws_size; // uses 512 KB of d_ws
    unsigned short* ws16 = (unsigned short*)d_ws;
    convW_kernel<<<512, 256, 0, stream>>>(Wr, Wn, ws16);
    router_mfma<<<MROWS / TILEM, 256, 0, stream>>>(X, ws16, br, bn, U, (float*)d_out);
}